// Round 1
// baseline (522.629 us; speedup 1.0000x reference)
//
#include <hip/hip_runtime.h>
#include <math.h>

#define C_DIM 128
#define BKT_SHIFT 7          // 128 nodes per destination bucket
#define MAX_B 1024           // bucket arrays capacity (B = ceil(N/128) = 782)
#define CB 256               // edge chunk blocks
#define CHUNK_MAX 6400       // per-block LDS sort capacity (chunk = 6252)
#define FB_CAP 8192          // bfinal LDS edge-staging capacity (avg bucket ~2048)
#define NSLICE 8             // channel slices: 16ch * 100k nodes * 2B = 3.2MB < 4MB XCD L2
#define SLICE_C 16           // channels per slice
#define POOL_ROWS 1024       // rows per pool block
typedef unsigned short ushort_t;
typedef __attribute__((ext_vector_type(8))) short short8;
typedef __attribute__((ext_vector_type(4))) float f32x4;
typedef __attribute__((ext_vector_type(2))) float f32x2;  // -> v_pk_add_f32
typedef __attribute__((ext_vector_type(4))) unsigned int u32x4;

static inline int ceil_div(int a, int b) { return (a + b - 1) / b; }

// bf16 round-to-nearest-even (unbiased — truncation would bias sums)
__device__ inline ushort_t f2bf(float f) {
    union { float f; unsigned u; } v; v.f = f;
    unsigned r = v.u + 0x7FFFu + ((v.u >> 16) & 1u);
    return (ushort_t)(r >> 16);
}
__device__ inline float bf2f(unsigned s) {
    union { unsigned u; float f; } v; v.u = s << 16; return v.f;
}
__device__ inline float bf_lo(unsigned u) {
    union { unsigned v; float f; } c; c.v = u << 16; return c.f;
}
__device__ inline float bf_hi(unsigned u) {
    union { unsigned v; float f; } c; c.v = u & 0xFFFF0000u; return c.f;
}
// packed accumulate: 2 unpack VALU + 1 v_pk_add_f32 per dword
__device__ inline void accum8pk(uint4 u, f32x2 ac[4]) {
    ac[0] += (f32x2){bf_lo(u.x), bf_hi(u.x)};
    ac[1] += (f32x2){bf_lo(u.y), bf_hi(u.y)};
    ac[2] += (f32x2){bf_lo(u.z), bf_hi(u.z)};
    ac[3] += (f32x2){bf_lo(u.w), bf_hi(u.w)};
}

// ============ CSR build: block-local LDS counting sort (dense writes) =======

// SINGLE global edge read: pass 1 loads row+col once, stages packed edge +
// bucket-id in LDS while histogramming; pass 2 is an LDS->LDS scatter; then a
// dense coalesced stream-out. Blocks CB..CB+1 pack weights instead.
__global__ __launch_bounds__(256) void k_sortchunk(
    const int* __restrict__ row, const int* __restrict__ col, int E, int chunk,
    int B, int* __restrict__ counts, int* __restrict__ sstart,
    int* __restrict__ epk,
    const float* __restrict__ W1, const float* __restrict__ W2,
    uint4* __restrict__ wf1, uint4* __restrict__ wf2,
    float* __restrict__ gsums, int GC, int* __restrict__ cursor) {
    int t = threadIdx.x, blk = blockIdx.x;
    if (blk >= CB) {   // weight fragment pre-pack
        const float* W = (blk == CB) ? W1 : W2;
        uint4* wf = (blk == CB) ? wf1 : wf2;
        for (int f = t; f < 2048; f += 256) {
            int lane = f & 63, kkn = f >> 6;
            int kk = kkn & 3, nt = kkn >> 2;
            int n = lane & 15, quad = lane >> 4;
            union { ushort_t h[8]; uint4 v; } u;
#pragma unroll
            for (int j = 0; j < 8; ++j)
                u.h[j] = f2bf(W[(size_t)(kk * 32 + quad * 8 + j) * C_DIM + nt * 16 + n]);
            wf[f] = u.v;
        }
        return;
    }
    // zero gsums + cursor (consumers run much later in the stream)
    for (int i = blk * 256 + t; i < GC; i += CB * 256) gsums[i] = 0.f;
    if (blk == 0 && t == 0) *cursor = 0;

    __shared__ int hist[MAX_B];                      // 4 KB
    __shared__ int hscan[MAX_B];                     // 4 KB
    __shared__ int sd[256];                          // 1 KB
    __shared__ __align__(16) int ebuf[CHUNK_MAX];    // 25.6 KB packed (r<<7)|(c&127)
    __shared__ __align__(8)  ushort_t bbuf[CHUNK_MAX]; // 12.8 KB bucket ids
    __shared__ int sorted[CHUNK_MAX];                // 25.6 KB

    for (int i = t; i < B; i += 256) hist[i] = 0;
    __syncthreads();
    int s = blk * chunk;                     // chunk % 4 == 0, E % 4 == 0
    int e = s + chunk; if (e > E) e = E;
    int cnt = e - s;                         // multiple of 4
    for (int i = s + 4 * t; i < e; i += 1024) {
        int4 c = *(const int4*)(col + i);
        int4 r = *(const int4*)(row + i);
        int li = i - s;
        int4 pk;
        pk.x = (r.x << 7) | (c.x & 127);
        pk.y = (r.y << 7) | (c.y & 127);
        pk.z = (r.z << 7) | (c.z & 127);
        pk.w = (r.w << 7) | (c.w & 127);
        *(int4*)&ebuf[li] = pk;
        ushort4 bk;
        bk.x = (ushort_t)(c.x >> BKT_SHIFT);
        bk.y = (ushort_t)(c.y >> BKT_SHIFT);
        bk.z = (ushort_t)(c.z >> BKT_SHIFT);
        bk.w = (ushort_t)(c.w >> BKT_SHIFT);
        *(ushort4*)&bbuf[li] = bk;
        atomicAdd(&hist[bk.x], 1);
        atomicAdd(&hist[bk.y], 1);
        atomicAdd(&hist[bk.z], 1);
        atomicAdd(&hist[bk.w], 1);
    }
    __syncthreads();
    // blocked exclusive scan of hist[0..B) -> hscan
    {
        int base4 = t * 4;
        int vv[4]; int sum = 0;
#pragma unroll
        for (int j = 0; j < 4; ++j) {
            int idx = base4 + j;
            vv[j] = (idx < B) ? hist[idx] : 0;
            sum += vv[j];
        }
        sd[t] = sum;
        __syncthreads();
        for (int off = 1; off < 256; off <<= 1) {
            int x = (t >= off) ? sd[t - off] : 0;
            __syncthreads();
            sd[t] += x;
            __syncthreads();
        }
        int run = sd[t] - sum;
#pragma unroll
        for (int j = 0; j < 4; ++j) {
            int idx = base4 + j;
            if (idx < B) hscan[idx] = run;
            run += vv[j];
        }
    }
    __syncthreads();
    for (int i = t; i < B; i += 256) {
        counts[(size_t)blk * MAX_B + i] = hist[i];
        sstart[(size_t)blk * MAX_B + i] = hscan[i];
    }
    __syncthreads();
    for (int i = t; i < B; i += 256) hist[i] = hscan[i];  // reuse as cursor
    __syncthreads();
    for (int i = t; i < cnt; i += 256) {
        int pos = atomicAdd(&hist[bbuf[i]], 1);
        sorted[pos] = ebuf[i];
    }
    __syncthreads();
    for (int i = t; i * 4 < cnt; i += 256)
        *(int4*)&epk[s + i * 4] = *(const int4*)&sorted[i * 4];
}

// Final: per bucket, self-claim csr base from cursor (order-free), gather its
// CB segments, LDS-stage, per-node count, scan, write (start,end)+dinv, csr.
// NEW: also emits an in-bucket degree-sorted permutation (perm) so the sliced
// aggregate's 32-nodes-per-wave mapping has near-uniform trip counts.
__global__ __launch_bounds__(256) void k_bfinal(
    const int* __restrict__ epk, const int* __restrict__ counts,
    const int* __restrict__ sstart, int* __restrict__ cursor,
    int chunk, int N,
    int2* __restrict__ offs2, float* __restrict__ dinv, int* __restrict__ csr,
    int* __restrict__ perm) {
    __shared__ int sh[FB_CAP];
    __shared__ int sd[256];
    __shared__ int cnt[128];
    __shared__ int pre[128];
    __shared__ int cur[128];
    __shared__ int dbin[64];
    __shared__ int dsc[64];
    __shared__ int dcur[64];
    __shared__ int sbase_s;
    int bkt = blockIdx.x, t = threadIdx.x;
    int base = bkt << BKT_SHIFT;
    int nn = N - base; if (nn > 128) nn = 128;

    int segln = counts[(size_t)t * MAX_B + bkt];
    int gs = t * chunk + sstart[(size_t)t * MAX_B + bkt];
    sd[t] = segln;
    __syncthreads();
    for (int off = 1; off < 256; off <<= 1) {
        int x = (t >= off) ? sd[t - off] : 0;
        __syncthreads();
        sd[t] += x;
        __syncthreads();
    }
    int place = sd[t] - segln;
    int m = sd[255];
    if (t == 255) sbase_s = atomicAdd(cursor, m);
    if (t < 128) cnt[t] = 0;
    __syncthreads();
    int sbase = sbase_s;

    bool fits = (m <= FB_CAP);
    if (fits) {
        for (int j = 0; j < segln; ++j) {
            int u = epk[gs + j];
            sh[place + j] = u;
            atomicAdd(&cnt[u & 127], 1);
        }
    } else {
        for (int j = 0; j < segln; ++j)
            atomicAdd(&cnt[epk[gs + j] & 127], 1);
    }
    __syncthreads();
    if (t < 128) pre[t] = cnt[t];
    __syncthreads();
    for (int off = 1; off < 128; off <<= 1) {
        int x = (t >= off && t < 128) ? pre[t - off] : 0;
        __syncthreads();
        if (t < 128) pre[t] += x;
        __syncthreads();
    }
    if (t < 128) {
        int ex = pre[t] - cnt[t];
        cur[t] = ex;
        if (t < nn) {
            offs2[base + t] = make_int2(sbase + ex, sbase + ex + cnt[t]);
            dinv[base + t] = 1.0f / sqrtf((float)cnt[t] + 1.0f);
        }
    }
    __syncthreads();
    if (fits) {
        for (int i = t; i < m; i += 256) {
            int u = sh[i];
            int slot = atomicAdd(&cur[u & 127], 1);
            csr[sbase + slot] = u >> 7;
        }
    } else {
        for (int j = 0; j < segln; ++j) {
            int u = epk[gs + j];
            int slot = atomicAdd(&cur[u & 127], 1);
            csr[sbase + slot] = u >> 7;
        }
    }
    // ---- in-bucket degree sort -> perm (pad slots dup last valid node) ----
    __syncthreads();
    if (t < 64) { dbin[t] = 0; dcur[t] = 0; }
    __syncthreads();
    int deg = 0, bidx = 0, tn = 0;
    if (t < 128) {
        tn = (t < nn) ? t : (nn - 1);
        deg = cnt[tn];
        bidx = deg > 63 ? 63 : deg;
        atomicAdd(&dbin[bidx], 1);
    }
    __syncthreads();
    if (t < 64) dsc[t] = dbin[t];
    __syncthreads();
    for (int off = 1; off < 64; off <<= 1) {
        int x = (t >= off && t < 64) ? dsc[t - off] : 0;
        __syncthreads();
        if (t < 64) dsc[t] += x;
        __syncthreads();
    }
    if (t < 128) {
        int rank = dsc[bidx] - dbin[bidx] + atomicAdd(&dcur[bidx], 1);
        perm[(bkt << 7) + rank] = base + tn;
    }
}

// ============ MFMA matmul [N,128]@[128,128] -> bf16 table, scaled by dinv ===
// Output (and ABF16 input) layout is CHANNEL-SLICED: [slice][node][16ch] bf16,
// slice pitch N*16 — one slice = 3.2MB, fits a per-XCD L2 for the aggregate.
template <int ABF16>
__global__ __launch_bounds__(256) void k_matmul_mfma(
    const float* __restrict__ Af, const ushort_t* __restrict__ Abf,
    const uint4* __restrict__ wfrag, const float* __restrict__ dinv,
    ushort_t* __restrict__ Cb, int N) {
    __shared__ uint4 wfs[2048];                       // 32 KB
    __shared__ __align__(16) ushort_t As[64 * 136];   // 17.4 KB (also epilogue)
    int t = threadIdx.x;
    int wv = t >> 6, lane = t & 63;
    int n = lane & 15, quad = lane >> 4;
    int row0 = blockIdx.x * 64;

    for (int i = t; i < 2048; i += 256) wfs[i] = wfrag[i];

    if (ABF16) {
        // sliced global read: 128 consecutive units per slice are contiguous
#pragma unroll
        for (int i = 0; i < 4; ++i) {
            int idx = i * 256 + t;
            int slice = idx >> 7;
            int uu = idx & 127;
            int r = uu >> 1, half = uu & 1;
            int grow = row0 + r; if (grow >= N) grow = N - 1;
            uint4 v = *(const uint4*)(Abf + (size_t)slice * N * SLICE_C +
                                      (size_t)grow * SLICE_C + half * 8);
            *(uint4*)&As[r * 136 + (slice * 2 + half) * 8] = v;
        }
    } else {
#pragma unroll
        for (int i = 0; i < 8; ++i) {
            int idx = i * 256 + t;
            int r = idx >> 5, cq = idx & 31;
            int grow = row0 + r; if (grow >= N) grow = N - 1;
            float4 f = *(const float4*)(Af + (size_t)grow * C_DIM + cq * 4);
            union { ushort_t h[4]; uint2 v; } c;
            c.h[0] = f2bf(f.x); c.h[1] = f2bf(f.y);
            c.h[2] = f2bf(f.z); c.h[3] = f2bf(f.w);
            *(uint2*)&As[r * 136 + cq * 4] = c.v;
        }
    }

    f32x4 acc[8];
#pragma unroll
    for (int i = 0; i < 8; ++i) acc[i] = (f32x4){0.f, 0.f, 0.f, 0.f};

    __syncthreads();

    int rl = wv * 16 + n;
#pragma unroll
    for (int kk = 0; kk < 4; ++kk) {
        union { uint4 v; short8 s; } ca;
        ca.v = *(const uint4*)&As[rl * 136 + kk * 32 + quad * 8];
#pragma unroll
        for (int nt = 0; nt < 8; ++nt) {
            union { uint4 v; short8 s; } cb;
            cb.v = wfs[(nt * 4 + kk) * 64 + lane];
            acc[nt] = __builtin_amdgcn_mfma_f32_16x16x32_bf16(ca.s, cb.s, acc[nt], 0, 0, 0);
        }
    }

    __syncthreads();
#pragma unroll
    for (int reg = 0; reg < 4; ++reg) {
        int lr = wv * 16 + quad * 4 + reg;
        int grow = row0 + lr;
        float sc = dinv[grow < N ? grow : N - 1];
#pragma unroll
        for (int nt = 0; nt < 8; ++nt)
            As[lr * 136 + nt * 16 + n] = f2bf(acc[nt][reg] * sc);
    }
    __syncthreads();
    int rows = N - row0; if (rows > 64) rows = 64;
    // sliced epilogue: per slice, 64 rows x 32B contiguous (2KB runs)
#pragma unroll
    for (int i = 0; i < 4; ++i) {
        int idx = i * 256 + t;
        int slice = idx >> 7;
        int uu = idx & 127;
        int r = uu >> 1, half = uu & 1;
        if (r < rows)
            *(uint4*)(Cb + (size_t)slice * N * SLICE_C +
                      (size_t)(row0 + r) * SLICE_C + half * 8) =
                *(const uint4*)&As[r * 136 + (slice * 2 + half) * 8];
    }
}

// ---------------- per-node gather-reduce aggregation (bf16 in/out) -----------
// CHANNEL-SLICED: grid = NSLICE x buckets, slice-major so all concurrently
// resident blocks work on ONE 3.2MB slice that every XCD L2 fully caches.
// Wave = 32 nodes x 2 lanes x 16B (32B/edge granule); each lane owns 8
// channels end-to-end (no cross-lane reduction). 48KB LDS pad caps occupancy
// at 3 blocks/CU so the in-flight node window stays within one slice.
template <int RELU>
__global__ __launch_bounds__(256, 3) void k_aggregate(
    const ushort_t* __restrict__ hs, const int2* __restrict__ offs2,
    const int* __restrict__ csr, const float* __restrict__ dinv,
    const int* __restrict__ perm, const float* __restrict__ bias,
    ushort_t* __restrict__ out, int N, int NB) {
    __shared__ int occ_pad[12288];     // 48 KB: 3 blocks/CU -> ~1 slice in flight
    int blk = blockIdx.x;
    if (N < 0) occ_pad[threadIdx.x] = blk;   // never true; keeps allocation
    int slice = blk / NB, bkt = blk - slice * NB;
    int t = threadIdx.x;
    int l = t & 63;
    int half = l & 1;
    int node = perm[(bkt << 7) + (t >> 6) * 32 + (l >> 1)];
    const ushort_t* hsl = hs + (size_t)slice * N * SLICE_C + half * 8;
    int2 se = offs2[node];

    f32x2 ac[4];
    {   // self-loop
        uint4 u = *(const uint4*)(hsl + (size_t)node * SLICE_C);
        ac[0] = (f32x2){bf_lo(u.x), bf_hi(u.x)};
        ac[1] = (f32x2){bf_lo(u.y), bf_hi(u.y)};
        ac[2] = (f32x2){bf_lo(u.z), bf_hi(u.z)};
        ac[3] = (f32x2){bf_lo(u.w), bf_hi(u.w)};
    }

    int j = se.x, e = se.y;
    for (; j + 4 <= e; j += 4) {        // 4 independent chains for MLP
        int r0 = __builtin_nontemporal_load(csr + j);
        int r1 = __builtin_nontemporal_load(csr + j + 1);
        int r2 = __builtin_nontemporal_load(csr + j + 2);
        int r3 = __builtin_nontemporal_load(csr + j + 3);
        uint4 u0 = *(const uint4*)(hsl + (size_t)r0 * SLICE_C);
        uint4 u1 = *(const uint4*)(hsl + (size_t)r1 * SLICE_C);
        uint4 u2 = *(const uint4*)(hsl + (size_t)r2 * SLICE_C);
        uint4 u3 = *(const uint4*)(hsl + (size_t)r3 * SLICE_C);
        accum8pk(u0, ac); accum8pk(u1, ac);
        accum8pk(u2, ac); accum8pk(u3, ac);
    }
    for (; j < e; ++j) {
        int r = __builtin_nontemporal_load(csr + j);
        uint4 u = *(const uint4*)(hsl + (size_t)r * SLICE_C);
        accum8pk(u, ac);
    }

    float dn = dinv[node];
    const float* bp = bias + slice * SLICE_C + half * 8;
    float4 b0 = *(const float4*)bp;
    float4 b1 = *(const float4*)(bp + 4);
    float o[8];
    o[0] = dn * ac[0].x + b0.x; o[1] = dn * ac[0].y + b0.y;
    o[2] = dn * ac[1].x + b0.z; o[3] = dn * ac[1].y + b0.w;
    o[4] = dn * ac[2].x + b1.x; o[5] = dn * ac[2].y + b1.y;
    o[6] = dn * ac[3].x + b1.z; o[7] = dn * ac[3].y + b1.w;
    if (RELU) {
#pragma unroll
        for (int i = 0; i < 8; ++i) o[i] = fmaxf(o[i], 0.f);
    }
    u32x4 pk;
    pk.x = (unsigned)f2bf(o[0]) | ((unsigned)f2bf(o[1]) << 16);
    pk.y = (unsigned)f2bf(o[2]) | ((unsigned)f2bf(o[3]) << 16);
    pk.z = (unsigned)f2bf(o[4]) | ((unsigned)f2bf(o[5]) << 16);
    pk.w = (unsigned)f2bf(o[6]) | ((unsigned)f2bf(o[7]) << 16);
    __builtin_nontemporal_store(pk,
        (u32x4*)(out + (size_t)slice * N * SLICE_C + (size_t)node * SLICE_C + half * 8));
}

// ---------------- pool stage 1: segmented partial sums (sliced bf16 in) ------
__global__ __launch_bounds__(128) void k_pool_sl(
    const ushort_t* __restrict__ h, const int* __restrict__ batch, int n,
    int nbp, float* __restrict__ sums) {
    int blk = blockIdx.x;
    int slice = blk / nbp, chunk = blk - slice * nbp;
    int r0 = chunk * POOL_ROWS;
    int r1 = r0 + POOL_ROWS; if (r1 > n) r1 = n;
    int t = threadIdx.x;
    int rr = t >> 3, cq = t & 7;           // 16 row-lanes x 8 dword-lanes
    const ushort_t* base = h + (size_t)slice * n * SLICE_C + cq * 2;
    float* sb = sums + slice * SLICE_C + cq * 2;
    f32x2 acc = (f32x2){0.f, 0.f};
    int curg = -1;
    for (int i = r0 + rr; i < r1; i += 16) {
        int g = batch[i];
        if (g != curg) {
            if (curg >= 0) {
                atomicAdd(&sb[(size_t)curg * C_DIM], acc.x);
                atomicAdd(&sb[(size_t)curg * C_DIM + 1], acc.y);
            }
            acc = (f32x2){0.f, 0.f}; curg = g;
        }
        unsigned u = __builtin_nontemporal_load((const unsigned*)(base + (size_t)i * SLICE_C));
        acc.x += bf_lo(u); acc.y += bf_hi(u);
    }
    if (curg >= 0) {
        atomicAdd(&sb[(size_t)curg * C_DIM], acc.x);
        atomicAdd(&sb[(size_t)curg * C_DIM + 1], acc.y);
    }
}

// ---------------- pool stage 2: mean + MLP (128->64->1) ----------------
__global__ __launch_bounds__(128) void k_mlp(
    const float* __restrict__ sums, const int* __restrict__ batch, int n,
    const float* __restrict__ Wm1, const float* __restrict__ bm1,
    const float* __restrict__ Wm2, const float* __restrict__ bm2,
    float* __restrict__ out) {
    int g = blockIdx.x;
    int t = threadIdx.x;
    int lo = 0, hi = n;
    while (lo < hi) { int m = (lo + hi) >> 1; if (batch[m] < g) lo = m + 1; else hi = m; }
    int start = lo;
    lo = start; hi = n;
    while (lo < hi) { int m = (lo + hi) >> 1; if (batch[m] < g + 1) lo = m + 1; else hi = m; }
    float cnt = (float)(lo - start);

    float mean = sums[(size_t)g * C_DIM + t] / fmaxf(cnt, 1.0f);

    __shared__ float m_s[128];
    __shared__ float hid[64];
    m_s[t] = mean;
    __syncthreads();
    if (t < 64) {
        float a = bm1[t];
#pragma unroll 4
        for (int k = 0; k < 128; ++k) a += m_s[k] * Wm1[k * 64 + t];
        hid[t] = fmaxf(a, 0.f) * Wm2[t];
    }
    __syncthreads();
    if (t < 64) {
        float v = hid[t];
        for (int off = 32; off > 0; off >>= 1) v += __shfl_down(v, off);
        if (t == 0) out[g] = v + bm2[0];
    }
}

extern "C" void kernel_launch(void* const* d_in, const int* in_sizes, int n_in,
                              void* d_out, int out_size, void* d_ws, size_t ws_size,
                              hipStream_t stream) {
    const float* x     = (const float*)d_in[0];
    const int*   eidx  = (const int*)d_in[1];
    const int*   batch = (const int*)d_in[2];
    const float* W1    = (const float*)d_in[3];
    const float* b1    = (const float*)d_in[4];
    const float* W2    = (const float*)d_in[5];
    const float* b2    = (const float*)d_in[6];
    const float* Wm1   = (const float*)d_in[7];
    const float* bm1   = (const float*)d_in[8];
    const float* Wm2   = (const float*)d_in[9];
    const float* bm2   = (const float*)d_in[10];

    const int N = in_sizes[2];       // 100000
    const int E = in_sizes[1] / 2;   // 1600000 (E % 4 == 0)
    const int G = out_size;          // 512
    const int B = (N + 127) >> BKT_SHIFT;   // 782 buckets

    char* p = (char*)d_ws;
    auto carve = [&](size_t bytes) {
        char* q = p;
        p += (bytes + 255) & ~(size_t)255;
        return q;
    };
    ushort_t* bufT   = (ushort_t*)carve((size_t)N * C_DIM * sizeof(ushort_t)); // matmul out
    ushort_t* bufA   = (ushort_t*)carve((size_t)N * C_DIM * sizeof(ushort_t)); // agg out
    float*    dinv   = (float*)   carve((size_t)N * sizeof(float));
    int2*     offs2  = (int2*)    carve((size_t)N * sizeof(int2));
    int*      csr    = (int*)     carve((size_t)E * sizeof(int));
    int*      counts = (int*)     carve((size_t)CB * MAX_B * sizeof(int));  // block-major
    int*      sstart = (int*)     carve((size_t)CB * MAX_B * sizeof(int));  // block-major
    float*    gsums  = (float*)   carve((size_t)G * C_DIM * sizeof(float));
    uint4*    wf1    = (uint4*)   carve(2048 * sizeof(uint4));
    uint4*    wf2    = (uint4*)   carve(2048 * sizeof(uint4));
    int*      cursor = (int*)     carve(sizeof(int));
    int*      perm   = (int*)     carve((size_t)B * 128 * sizeof(int));
    // epk (packed (src<<7)|node7, 6.4 MB, block-dense) aliases bufT
    int*      epk    = (int*)bufT;

    const int* erow = eidx;
    const int* ecol = eidx + E;
    const int chunk = (ceil_div(E, CB) + 3) & ~3;   // 6252, fits CHUNK_MAX

    // --- CSR build: LDS counting sort, single edge read, dense writes ---
    k_sortchunk<<<CB + 2, 256, 0, stream>>>(erow, ecol, E, chunk, B,
                                            counts, sstart, epk,
                                            W1, W2, wf1, wf2, gsums, G * C_DIM, cursor);
    k_bfinal<<<B, 256, 0, stream>>>(epk, counts, sstart, cursor, chunk, N,
                                    offs2, dinv, csr, perm);

    // --- conv1 ---
    k_matmul_mfma<0><<<ceil_div(N, 64), 256, 0, stream>>>(x, nullptr, wf1, dinv, bufT, N);
    k_aggregate<1><<<NSLICE * B, 256, 0, stream>>>(bufT, offs2, csr, dinv, perm, b1,
                                                   bufA, N, B);
    // --- conv2 ---
    k_matmul_mfma<1><<<ceil_div(N, 64), 256, 0, stream>>>(nullptr, bufA, wf2, dinv, bufT, N);
    k_aggregate<0><<<NSLICE * B, 256, 0, stream>>>(bufT, offs2, csr, dinv, perm, b2,
                                                   bufA, N, B);
    // --- pool (2-stage) + MLP ---
    const int nbp = ceil_div(N, POOL_ROWS);
    k_pool_sl<<<NSLICE * nbp, 128, 0, stream>>>(bufA, batch, N, nbp, gsums);
    k_mlp<<<G, 128, 0, stream>>>(gsums, batch, N, Wm1, bm1, Wm2, bm2, (float*)d_out);
}